// Round 1
// baseline (577.437 us; speedup 1.0000x reference)
//
#include <hip/hip_runtime.h>
#include <hip/hip_fp16.h>

typedef _Float16 f16x8 __attribute__((ext_vector_type(8)));
typedef float    f32x4 __attribute__((ext_vector_type(4)));

#define MFMA16(a,b,c) __builtin_amdgcn_mfma_f32_16x16x32_f16(a,b,c,0,0,0)

__device__ __forceinline__ void gload_lds16(const void* g, void* l) {
  __builtin_amdgcn_global_load_lds(
      (const __attribute__((address_space(1))) void*)g,
      (__attribute__((address_space(3))) void*)l, 16, 0, 0);
}

// ---------------- fp32 -> fp16 conversion ----------------
__global__ void cvt_f32_f16(const float* __restrict__ src,
                            _Float16* __restrict__ dst, int n8) {
  int i = blockIdx.x * blockDim.x + threadIdx.x;
  int stride = gridDim.x * blockDim.x;
  for (; i < n8; i += stride) {
    const float4* s = (const float4*)src + 2 * (size_t)i;
    float4 a = s[0], b = s[1];
    f16x8 o;
    o[0]=(_Float16)a.x; o[1]=(_Float16)a.y; o[2]=(_Float16)a.z; o[3]=(_Float16)a.w;
    o[4]=(_Float16)b.x; o[5]=(_Float16)b.y; o[6]=(_Float16)b.z; o[7]=(_Float16)b.w;
    ((f16x8*)dst)[i] = o;
  }
}

// ---------------- fused QKV projection GEMM ----------------
// C[512,12288] = X16[512,4096] @ W16[12288,4096]^T  (NT, both K-contiguous)
// n in [0,4096): q -> Q16[h][m][d]; [4096,8192): k -> Kc[h][P+m][d];
// [8192,12288): v -> Vc[h][P+m][d]
__global__ __launch_bounds__(256) void qkv_gemm(
    const _Float16* __restrict__ X,
    const _Float16* __restrict__ W,
    _Float16* __restrict__ Q16,
    _Float16* __restrict__ Kc,
    _Float16* __restrict__ Vc,
    const int* __restrict__ Pp)
{
  __shared__ __align__(16) _Float16 As[128][32];
  __shared__ __align__(16) _Float16 Bs[128][32];
  const int bid = blockIdx.x;
  const int mt = bid & 3, nt = bid >> 2;       // 4 m-tiles x 96 n-tiles; n fastest-varying -> W-band reuse
  const int m0 = mt * 128, n0 = nt * 128;
  const int tid = threadIdx.x, wave = tid >> 6, lane = tid & 63;
  const int g = lane >> 4, c = lane & 15;
  const int wr = wave >> 1, wc = wave & 1;
  f32x4 acc[4][4] = {};
  const _Float16* ga = X + (size_t)(m0 + wave * 32 + (lane >> 2)) * 4096 + (lane & 3) * 8;
  const _Float16* gb = W + (size_t)(n0 + wave * 32 + (lane >> 2)) * 4096 + (lane & 3) * 8;
  _Float16* la = &As[wave * 32][0];
  _Float16* lb = &Bs[wave * 32][0];
  for (int k0 = 0; k0 < 4096; k0 += 32) {
    __syncthreads();
    gload_lds16(ga + k0,             la);
    gload_lds16(ga + k0 + 16 * 4096, la + 16 * 32);
    gload_lds16(gb + k0,             lb);
    gload_lds16(gb + k0 + 16 * 4096, lb + 16 * 32);
    __syncthreads();
    f16x8 af[4], bf[4];
#pragma unroll
    for (int mi = 0; mi < 4; mi++) af[mi] = *(const f16x8*)&As[wr * 64 + mi * 16 + c][g * 8];
#pragma unroll
    for (int ni = 0; ni < 4; ni++) bf[ni] = *(const f16x8*)&Bs[wc * 64 + ni * 16 + c][g * 8];
#pragma unroll
    for (int mi = 0; mi < 4; mi++)
#pragma unroll
      for (int ni = 0; ni < 4; ni++)
        acc[mi][ni] = MFMA16(af[mi], bf[ni], acc[mi][ni]);
  }
  const int p = Pp[0];
  const int wsel = n0 >> 12;
  const int h = (n0 >> 7) & 31;
#pragma unroll
  for (int mi = 0; mi < 4; mi++) {
#pragma unroll
    for (int ni = 0; ni < 4; ni++) {
#pragma unroll
      for (int j = 0; j < 4; j++) {
        int m = m0 + wr * 64 + mi * 16 + 4 * g + j;
        int d = wc * 64 + ni * 16 + c;
        _Float16 hv = (_Float16)acc[mi][ni][j];
        if (wsel == 0)      Q16[(size_t)(h * 512 + m) * 128 + d] = hv;
        else if (wsel == 1) Kc[(size_t)(h * 4096 + p + m) * 128 + d] = hv;
        else                Vc[(size_t)(h * 4096 + p + m) * 128 + d] = hv;
      }
    }
  }
}

// ---------------- flash attention ----------------
// grid = 32 heads x 8 m-tiles (BM=64); 4 waves x 16 q-rows; BL=128
__global__ __launch_bounds__(256) void attn_fwd(
    const _Float16* __restrict__ Q16,
    const _Float16* __restrict__ Kc,
    const _Float16* __restrict__ Vc,
    float* __restrict__ out)
{
  __shared__ __align__(16) _Float16 Vt[128][136];     // [d][l], stride 136 (16B aligned, bank-spread)
  __shared__ __align__(16) _Float16 Pl[4][16][136];   // per-wave P tile
  const int h = blockIdx.x >> 3, mt = blockIdx.x & 7;
  const int m0 = mt * 64;
  const int tid = threadIdx.x, wave = tid >> 6, lane = tid & 63;
  const int g = lane >> 4, c = lane & 15;
  const _Float16* Qp = Q16 + (size_t)(h * 512 + m0 + wave * 16 + c) * 128;
  f16x8 qf[4];
#pragma unroll
  for (int kc = 0; kc < 4; kc++) qf[kc] = *(const f16x8*)&Qp[kc * 32 + g * 8];
  const _Float16* Kh = Kc + (size_t)h * 4096 * 128;
  const _Float16* Vh = Vc + (size_t)h * 4096 * 128;
  f32x4 o[8] = {};
  float mrow[4] = {-3e38f, -3e38f, -3e38f, -3e38f};
  float lrow[4] = {0.f, 0.f, 0.f, 0.f};
  const int lb = (tid & 15) * 8, db = (tid >> 4) * 8;

  for (int l0 = 0; l0 < 4096; l0 += 128) {
    __syncthreads();  // prev PV done with Vt/Pl
    // ---- stage V transposed: Vt[d][l] ----
    {
      uint4 rr[8];
#pragma unroll
      for (int e = 0; e < 8; e++)
        rr[e] = *(const uint4*)&Vh[(size_t)(l0 + lb + e) * 128 + db];
      const unsigned short* s = (const unsigned short*)rr;
#pragma unroll
      for (int d2 = 0; d2 < 8; d2++) {
        unsigned u0 = (unsigned)s[0 * 8 + d2] | ((unsigned)s[1 * 8 + d2] << 16);
        unsigned u1 = (unsigned)s[2 * 8 + d2] | ((unsigned)s[3 * 8 + d2] << 16);
        unsigned u2 = (unsigned)s[4 * 8 + d2] | ((unsigned)s[5 * 8 + d2] << 16);
        unsigned u3 = (unsigned)s[6 * 8 + d2] | ((unsigned)s[7 * 8 + d2] << 16);
        uint4 w; w.x = u0; w.y = u1; w.z = u2; w.w = u3;
        *(uint4*)&Vt[db + d2][lb] = w;
      }
    }
    // ---- scores S[16 q-rows][128 kl] via MFMA, K direct from global (L2/L3) ----
    f32x4 sc[8] = {};
#pragma unroll
    for (int ni = 0; ni < 8; ni++) {
#pragma unroll
      for (int kc = 0; kc < 4; kc++) {
        f16x8 kf = *(const f16x8*)&Kh[(size_t)(l0 + ni * 16 + c) * 128 + kc * 32 + g * 8];
        sc[ni] = MFMA16(qf[kc], kf, sc[ni]);
      }
    }
    // ---- online softmax (rows 4g+j, reduce over 16-lane c-group) ----
    float scale[4];
#pragma unroll
    for (int j = 0; j < 4; j++) {
      float tm = sc[0][j];
#pragma unroll
      for (int ni = 1; ni < 8; ni++) tm = fmaxf(tm, sc[ni][j]);
      tm = fmaxf(tm, __shfl_xor(tm, 1, 64));
      tm = fmaxf(tm, __shfl_xor(tm, 2, 64));
      tm = fmaxf(tm, __shfl_xor(tm, 4, 64));
      tm = fmaxf(tm, __shfl_xor(tm, 8, 64));
      float mn = fmaxf(mrow[j], tm);
      scale[j] = __expf(mrow[j] - mn);
      mrow[j] = mn;
    }
    float rs[4] = {0.f, 0.f, 0.f, 0.f};
#pragma unroll
    for (int ni = 0; ni < 8; ni++) {
#pragma unroll
      for (int j = 0; j < 4; j++) {
        float pv = __expf(sc[ni][j] - mrow[j]);
        sc[ni][j] = pv;
        rs[j] += pv;
      }
    }
#pragma unroll
    for (int j = 0; j < 4; j++) {
      rs[j] += __shfl_xor(rs[j], 1, 64);
      rs[j] += __shfl_xor(rs[j], 2, 64);
      rs[j] += __shfl_xor(rs[j], 4, 64);
      rs[j] += __shfl_xor(rs[j], 8, 64);
      lrow[j] = lrow[j] * scale[j] + rs[j];
    }
#pragma unroll
    for (int dn = 0; dn < 8; dn++)
#pragma unroll
      for (int j = 0; j < 4; j++) o[dn][j] *= scale[j];
    // ---- write P tile to LDS (row = 4g+j, col = ni*16+c) ----
#pragma unroll
    for (int ni = 0; ni < 8; ni++)
#pragma unroll
      for (int j = 0; j < 4; j++)
        Pl[wave][4 * g + j][ni * 16 + c] = (_Float16)sc[ni][j];
    __syncthreads();  // Vt + Pl ready
    // ---- PV: o[qr][d] += P[qr][l] * V[l][d] ----
    f16x8 pa[4];
#pragma unroll
    for (int kc = 0; kc < 4; kc++)
      pa[kc] = *(const f16x8*)&Pl[wave][c][kc * 32 + g * 8];
#pragma unroll
    for (int dn = 0; dn < 8; dn++) {
#pragma unroll
      for (int kc = 0; kc < 4; kc++) {
        f16x8 vb = *(const f16x8*)&Vt[dn * 16 + c][kc * 32 + g * 8];
        o[dn] = MFMA16(pa[kc], vb, o[dn]);
      }
    }
  }
  // ---- epilogue: out[m][h*128+d] = o / l ----
#pragma unroll
  for (int dn = 0; dn < 8; dn++) {
#pragma unroll
    for (int j = 0; j < 4; j++) {
      int m = m0 + wave * 16 + 4 * g + j;
      out[(size_t)m * 4096 + h * 128 + dn * 16 + c] = o[dn][j] / lrow[j];
    }
  }
}

extern "C" void kernel_launch(void* const* d_in, const int* in_sizes, int n_in,
                              void* d_out, int out_size, void* d_ws, size_t ws_size,
                              hipStream_t stream) {
  const float* X  = (const float*)d_in[0];
  const float* Wq = (const float*)d_in[1];
  const float* Wk = (const float*)d_in[2];
  const float* Wv = (const float*)d_in[3];
  const float* cK = (const float*)d_in[4];
  const float* cV = (const float*)d_in[5];
  const int*   Pp = (const int*)d_in[6];
  float* out = (float*)d_out;

  char* ws = (char*)d_ws;
  _Float16* X16 = (_Float16*)(ws);                            // 4 MB
  _Float16* W16 = (_Float16*)(ws + ((size_t)4   << 20));      // 96 MB  [12288][4096]
  _Float16* Q16 = (_Float16*)(ws + ((size_t)100 << 20));      // 4 MB   [32][512][128]
  _Float16* K16 = (_Float16*)(ws + ((size_t)104 << 20));      // 32 MB  [32][4096][128]
  _Float16* V16 = (_Float16*)(ws + ((size_t)136 << 20));      // 32 MB  -> 168 MB total

  const int NTH = 256;
  auto cvtl = [&](const float* s, _Float16* d, size_t n) {
    int n8 = (int)(n / 8);
    int grid = (n8 + NTH - 1) / NTH;
    if (grid > 2048) grid = 2048;
    cvt_f32_f16<<<dim3(grid), dim3(NTH), 0, stream>>>(s, d, n8);
  };
  cvtl(X,  X16, (size_t)512 * 4096);
  cvtl(Wq, W16,                          (size_t)4096 * 4096);
  cvtl(Wk, W16 + (size_t)4096 * 4096,    (size_t)4096 * 4096);
  cvtl(Wv, W16 + (size_t)2 * 4096 * 4096,(size_t)4096 * 4096);
  cvtl(cK, K16, (size_t)32 * 4096 * 128);
  cvtl(cV, V16, (size_t)32 * 4096 * 128);

  qkv_gemm<<<dim3(384), dim3(256), 0, stream>>>(X16, W16, Q16, K16, V16, Pp);
  attn_fwd<<<dim3(256), dim3(256), 0, stream>>>(Q16, K16, V16, out);
}

// Round 2
// 405.152 us; speedup vs baseline: 1.4252x; 1.4252x over previous
//
#include <hip/hip_runtime.h>
#include <hip/hip_fp16.h>

typedef _Float16 f16x8 __attribute__((ext_vector_type(8)));
typedef float    f32x4 __attribute__((ext_vector_type(4)));

#define MFMA16(a,b,c) __builtin_amdgcn_mfma_f32_16x16x32_f16(a,b,c,0,0,0)

__device__ __forceinline__ void gload_lds16(const void* g, void* l) {
  __builtin_amdgcn_global_load_lds(
      (const __attribute__((address_space(1))) void*)g,
      (__attribute__((address_space(3))) void*)l, 16, 0, 0);
}

// ---------------- fp32 -> fp16 conversion ----------------
__global__ void cvt_f32_f16(const float* __restrict__ src,
                            _Float16* __restrict__ dst, int n8) {
  int i = blockIdx.x * blockDim.x + threadIdx.x;
  int stride = gridDim.x * blockDim.x;
  for (; i < n8; i += stride) {
    const float4* s = (const float4*)src + 2 * (size_t)i;
    float4 a = s[0], b = s[1];
    f16x8 o;
    o[0]=(_Float16)a.x; o[1]=(_Float16)a.y; o[2]=(_Float16)a.z; o[3]=(_Float16)a.w;
    o[4]=(_Float16)b.x; o[5]=(_Float16)b.y; o[6]=(_Float16)b.z; o[7]=(_Float16)b.w;
    ((f16x8*)dst)[i] = o;
  }
}

// ---------------- fused QKV projection GEMM ----------------
// C[512,12288] = X16[512,4096] @ W16[12288,4096]^T  (NT, both K-contiguous)
__global__ __launch_bounds__(256) void qkv_gemm(
    const _Float16* __restrict__ X,
    const _Float16* __restrict__ W,
    _Float16* __restrict__ Q16,
    _Float16* __restrict__ Kc,
    _Float16* __restrict__ Vc,
    const int* __restrict__ Pp)
{
  __shared__ __align__(16) _Float16 As[128][32];
  __shared__ __align__(16) _Float16 Bs[128][32];
  const int bid = blockIdx.x;
  const int mt = bid & 3, nt = bid >> 2;
  const int m0 = mt * 128, n0 = nt * 128;
  const int tid = threadIdx.x, wave = tid >> 6, lane = tid & 63;
  const int g = lane >> 4, c = lane & 15;
  const int wr = wave >> 1, wc = wave & 1;
  f32x4 acc[4][4] = {};
  const _Float16* ga = X + (size_t)(m0 + wave * 32 + (lane >> 2)) * 4096 + (lane & 3) * 8;
  const _Float16* gb = W + (size_t)(n0 + wave * 32 + (lane >> 2)) * 4096 + (lane & 3) * 8;
  _Float16* la = &As[wave * 32][0];
  _Float16* lb = &Bs[wave * 32][0];
  for (int k0 = 0; k0 < 4096; k0 += 32) {
    __syncthreads();
    gload_lds16(ga + k0,             la);
    gload_lds16(ga + k0 + 16 * 4096, la + 16 * 32);
    gload_lds16(gb + k0,             lb);
    gload_lds16(gb + k0 + 16 * 4096, lb + 16 * 32);
    __syncthreads();
    f16x8 af[4], bf[4];
#pragma unroll
    for (int mi = 0; mi < 4; mi++) af[mi] = *(const f16x8*)&As[wr * 64 + mi * 16 + c][g * 8];
#pragma unroll
    for (int ni = 0; ni < 4; ni++) bf[ni] = *(const f16x8*)&Bs[wc * 64 + ni * 16 + c][g * 8];
#pragma unroll
    for (int mi = 0; mi < 4; mi++)
#pragma unroll
      for (int ni = 0; ni < 4; ni++)
        acc[mi][ni] = MFMA16(af[mi], bf[ni], acc[mi][ni]);
  }
  const int p = Pp[0];
  const int wsel = n0 >> 12;
  const int h = (n0 >> 7) & 31;
#pragma unroll
  for (int mi = 0; mi < 4; mi++) {
#pragma unroll
    for (int ni = 0; ni < 4; ni++) {
#pragma unroll
      for (int j = 0; j < 4; j++) {
        int m = m0 + wr * 64 + mi * 16 + 4 * g + j;
        int d = wc * 64 + ni * 16 + c;
        _Float16 hv = (_Float16)acc[mi][ni][j];
        if (wsel == 0)      Q16[(size_t)(h * 512 + m) * 128 + d] = hv;
        else if (wsel == 1) Kc[(size_t)(h * 4096 + p + m) * 128 + d] = hv;
        else                Vc[(size_t)(h * 4096 + p + m) * 128 + d] = hv;
      }
    }
  }
}

// ---------------- flash attention, split-L partials ----------------
// grid = 4 lsplits x 32 heads x 8 m-tiles; each block: 64 q-rows x 1024 cache pos
__global__ __launch_bounds__(256) void attn_part(
    const _Float16* __restrict__ Q16,
    const _Float16* __restrict__ Kc,
    const _Float16* __restrict__ Vc,
    float* __restrict__ Opart,    // [4][32][512][128] unnormalized
    float* __restrict__ Mpart,    // [4][32][512]
    float* __restrict__ Lpart)    // [4][32][512]
{
  __shared__ __align__(16) _Float16 Vt[128][136];     // [d][l]
  __shared__ __align__(16) _Float16 Pl[4][16][136];   // per-wave P tile
  const int bid = blockIdx.x;
  const int ls = bid >> 8;
  const int h  = (bid >> 3) & 31;
  const int mt = bid & 7;
  const int m0 = mt * 64;
  const int tid = threadIdx.x, wave = tid >> 6, lane = tid & 63;
  const int g = lane >> 4, c = lane & 15;
  const _Float16* Qp = Q16 + (size_t)(h * 512 + m0 + wave * 16 + c) * 128;
  f16x8 qf[4];
#pragma unroll
  for (int kc = 0; kc < 4; kc++) qf[kc] = *(const f16x8*)&Qp[kc * 32 + g * 8];
  const _Float16* Kh = Kc + (size_t)h * 4096 * 128;
  const _Float16* Vh = Vc + (size_t)h * 4096 * 128;
  f32x4 o[8] = {};
  float mrow[4] = {-3e38f, -3e38f, -3e38f, -3e38f};
  float lrow[4] = {0.f, 0.f, 0.f, 0.f};
  const int lb = (tid & 15) * 8, db = (tid >> 4) * 8;
  const int l_begin = ls * 1024, l_end = l_begin + 1024;

  for (int l0 = l_begin; l0 < l_end; l0 += 128) {
    __syncthreads();  // prev PV done with Vt/Pl
    // ---- issue V loads early (latency hidden under QK^T) ----
    uint4 rr[8];
#pragma unroll
    for (int e = 0; e < 8; e++)
      rr[e] = *(const uint4*)&Vh[(size_t)(l0 + lb + e) * 128 + db];
    // ---- scores S[16 q-rows][128 kl] via MFMA, K direct from global (L2/L3) ----
    f32x4 sc[8] = {};
#pragma unroll
    for (int ni = 0; ni < 8; ni++) {
#pragma unroll
      for (int kc = 0; kc < 4; kc++) {
        f16x8 kf = *(const f16x8*)&Kh[(size_t)(l0 + ni * 16 + c) * 128 + kc * 32 + g * 8];
        sc[ni] = MFMA16(qf[kc], kf, sc[ni]);
      }
    }
    // ---- transpose V into LDS (loads landed by now) ----
    {
      const unsigned short* s = (const unsigned short*)rr;
#pragma unroll
      for (int d2 = 0; d2 < 8; d2++) {
        unsigned u0 = (unsigned)s[0 * 8 + d2] | ((unsigned)s[1 * 8 + d2] << 16);
        unsigned u1 = (unsigned)s[2 * 8 + d2] | ((unsigned)s[3 * 8 + d2] << 16);
        unsigned u2 = (unsigned)s[4 * 8 + d2] | ((unsigned)s[5 * 8 + d2] << 16);
        unsigned u3 = (unsigned)s[6 * 8 + d2] | ((unsigned)s[7 * 8 + d2] << 16);
        uint4 w; w.x = u0; w.y = u1; w.z = u2; w.w = u3;
        *(uint4*)&Vt[db + d2][lb] = w;
      }
    }
    // ---- online softmax (rows 4g+j, reduce over 16-lane c-group) ----
    float scale[4];
#pragma unroll
    for (int j = 0; j < 4; j++) {
      float tm = sc[0][j];
#pragma unroll
      for (int ni = 1; ni < 8; ni++) tm = fmaxf(tm, sc[ni][j]);
      tm = fmaxf(tm, __shfl_xor(tm, 1, 64));
      tm = fmaxf(tm, __shfl_xor(tm, 2, 64));
      tm = fmaxf(tm, __shfl_xor(tm, 4, 64));
      tm = fmaxf(tm, __shfl_xor(tm, 8, 64));
      float mn = fmaxf(mrow[j], tm);
      scale[j] = __expf(mrow[j] - mn);
      mrow[j] = mn;
    }
    float rs[4] = {0.f, 0.f, 0.f, 0.f};
#pragma unroll
    for (int ni = 0; ni < 8; ni++) {
#pragma unroll
      for (int j = 0; j < 4; j++) {
        float pv = __expf(sc[ni][j] - mrow[j]);
        sc[ni][j] = pv;
        rs[j] += pv;
      }
    }
#pragma unroll
    for (int j = 0; j < 4; j++) {
      rs[j] += __shfl_xor(rs[j], 1, 64);
      rs[j] += __shfl_xor(rs[j], 2, 64);
      rs[j] += __shfl_xor(rs[j], 4, 64);
      rs[j] += __shfl_xor(rs[j], 8, 64);
      lrow[j] = lrow[j] * scale[j] + rs[j];
    }
#pragma unroll
    for (int dn = 0; dn < 8; dn++)
#pragma unroll
      for (int j = 0; j < 4; j++) o[dn][j] *= scale[j];
    // ---- write P tile to LDS ----
#pragma unroll
    for (int ni = 0; ni < 8; ni++)
#pragma unroll
      for (int j = 0; j < 4; j++)
        Pl[wave][4 * g + j][ni * 16 + c] = (_Float16)sc[ni][j];
    __syncthreads();  // Vt + Pl ready
    // ---- PV: o[qr][d] += P[qr][l] * V[l][d] ----
    f16x8 pa[4];
#pragma unroll
    for (int kc = 0; kc < 4; kc++)
      pa[kc] = *(const f16x8*)&Pl[wave][c][kc * 32 + g * 8];
#pragma unroll
    for (int dn = 0; dn < 8; dn++) {
#pragma unroll
      for (int kc = 0; kc < 4; kc++) {
        f16x8 vb = *(const f16x8*)&Vt[dn * 16 + c][kc * 32 + g * 8];
        o[dn] = MFMA16(pa[kc], vb, o[dn]);
      }
    }
  }
  // ---- epilogue: write unnormalized partials ----
  const size_t pbase = ((size_t)(ls * 32 + h) * 512);
#pragma unroll
  for (int dn = 0; dn < 8; dn++) {
#pragma unroll
    for (int j = 0; j < 4; j++) {
      int m = m0 + wave * 16 + 4 * g + j;
      Opart[(pbase + m) * 128 + dn * 16 + c] = o[dn][j];
    }
  }
  if (c == 0) {
#pragma unroll
    for (int j = 0; j < 4; j++) {
      int m = m0 + wave * 16 + 4 * g + j;
      Mpart[pbase + m] = mrow[j];
      Lpart[pbase + m] = lrow[j];
    }
  }
}

// ---------------- combine 4 split-L partials ----------------
__global__ __launch_bounds__(256) void attn_combine(
    const float* __restrict__ Opart,
    const float* __restrict__ Mpart,
    const float* __restrict__ Lpart,
    float* __restrict__ out)
{
  int idx = blockIdx.x * 256 + threadIdx.x;   // 32*512*32 = 524288 float4s
  int row = idx >> 5;          // h*512 + m
  int d4  = idx & 31;
  int h = row >> 9, m = row & 511;
  float Ms[4];
  float mx = -3e38f;
#pragma unroll
  for (int s = 0; s < 4; s++) {
    Ms[s] = Mpart[(size_t)(s * 32 + h) * 512 + m];
    mx = fmaxf(mx, Ms[s]);
  }
  float lsum = 0.f;
  float4 acc = make_float4(0.f, 0.f, 0.f, 0.f);
#pragma unroll
  for (int s = 0; s < 4; s++) {
    float w = __expf(Ms[s] - mx);
    lsum += w * Lpart[(size_t)(s * 32 + h) * 512 + m];
    float4 ov = ((const float4*)(Opart + ((size_t)(s * 32 + h) * 512 + m) * 128))[d4];
    acc.x += w * ov.x; acc.y += w * ov.y; acc.z += w * ov.z; acc.w += w * ov.w;
  }
  float inv = 1.f / lsum;
  float4 r = make_float4(acc.x * inv, acc.y * inv, acc.z * inv, acc.w * inv);
  *(float4*)&out[(size_t)m * 4096 + h * 128 + d4 * 4] = r;
}

extern "C" void kernel_launch(void* const* d_in, const int* in_sizes, int n_in,
                              void* d_out, int out_size, void* d_ws, size_t ws_size,
                              hipStream_t stream) {
  const float* X  = (const float*)d_in[0];
  const float* Wq = (const float*)d_in[1];
  const float* Wk = (const float*)d_in[2];
  const float* Wv = (const float*)d_in[3];
  const float* cK = (const float*)d_in[4];
  const float* cV = (const float*)d_in[5];
  const int*   Pp = (const int*)d_in[6];
  float* out = (float*)d_out;

  char* ws = (char*)d_ws;
  _Float16* X16 = (_Float16*)(ws);                            // 4 MB
  _Float16* W16 = (_Float16*)(ws + ((size_t)4   << 20));      // 96 MB  [12288][4096]
  _Float16* Q16 = (_Float16*)(ws + ((size_t)100 << 20));      // 4 MB
  _Float16* K16 = (_Float16*)(ws + ((size_t)104 << 20));      // 32 MB
  _Float16* V16 = (_Float16*)(ws + ((size_t)136 << 20));      // 32 MB -> 168 MB total
  // partials alias the W16 region (W16 dead after qkv_gemm)
  float* Opart = (float*)(ws + ((size_t)4  << 20));           // 32 MB
  float* Mpart = (float*)(ws + ((size_t)36 << 20));           // 256 KB
  float* Lpart = (float*)(ws + ((size_t)37 << 20));           // 256 KB

  const int NTH = 256;
  auto cvtl = [&](const float* s, _Float16* d, size_t n) {
    int n8 = (int)(n / 8);
    int grid = (n8 + NTH - 1) / NTH;
    if (grid > 2048) grid = 2048;
    cvt_f32_f16<<<dim3(grid), dim3(NTH), 0, stream>>>(s, d, n8);
  };
  cvtl(X,  X16, (size_t)512 * 4096);
  cvtl(Wq, W16,                          (size_t)4096 * 4096);
  cvtl(Wk, W16 + (size_t)4096 * 4096,    (size_t)4096 * 4096);
  cvtl(Wv, W16 + (size_t)2 * 4096 * 4096,(size_t)4096 * 4096);
  cvtl(cK, K16, (size_t)32 * 4096 * 128);
  cvtl(cV, V16, (size_t)32 * 4096 * 128);

  qkv_gemm<<<dim3(384), dim3(256), 0, stream>>>(X16, W16, Q16, K16, V16, Pp);
  attn_part<<<dim3(1024), dim3(256), 0, stream>>>(Q16, K16, V16, Opart, Mpart, Lpart);
  attn_combine<<<dim3(2048), dim3(256), 0, stream>>>(Opart, Mpart, Lpart, out);
}